// Round 8
// baseline (350.742 us; speedup 1.0000x reference)
//
#include <hip/hip_runtime.h>
#include <hip/hip_cooperative_groups.h>

namespace cg = cooperative_groups;

// PatchMatch stereo — MI355X (gfx950), fused cooperative version (R7).
// B=1, C=32, H=128, W=256, S=12, FILTER=3, TEMP=7, ITERATIONS=2
// R7 restructuring: the channel dot-products are noise-independent, so build
// a banded cost volume ONCE:  CV[h][w][k] = dot(L[:,h,w], R[:,h,xr]),
// xr = w - KOFF + k, k in [0,80)  (f16, 5.2MB in ws). Every tap in all 4
// rounds then costs 2 f16 global loads + 3 flops instead of 16 ds_read2 +
// 32 fdot2 (4.7M taps reuse 2.5M precomputed dots). v0/v1 edge masks fold
// into CV=0 at out-of-range xr. 3 grid.sync()s; r1->r2 passes noise via LDS.
// Grid 768 blocks (128 rows x 6), launch_bounds(256,3): coop guaranteed.

namespace {
constexpr int C = 32;
constexpr int H = 128;
constexpr int W = 256;
constexpr int S = 12;
constexpr int SG = 2;                 // s-groups per block
constexpr int GY = S / SG;            // 6
constexpr int HW = H * W;
constexpr int C2 = C / 2;             // 16 packed channel-pair rows
constexpr int PP = 264;               // sP words/row: [0..3]=pad, [4..259]=x 0..255, [260..263]=pad
constexpr int NPITCH = W + 2;         // LDS noise row: 1 front, 1 back pad
constexpr int KD = 80;                // cost-volume band width (k = xr - w + KOFF)
constexpr int KOFF = 76;
constexpr int KPB = 14;               // k's per block in build (6*14=84 covers 80)
constexpr float TEMP_OVER_C = 7.0f / 32.0f;
constexpr float INTERVAL = 1.0f / (S + 1);

typedef _Float16 v2h __attribute__((ext_vector_type(2)));
}

__device__ __forceinline__ float fdot2_acc(v2h a, v2h b, float c) {
#if defined(__has_builtin) && __has_builtin(__builtin_amdgcn_fdot2)
    return __builtin_amdgcn_fdot2(a, b, c, false);
#else
    return c + (float)a.x * (float)b.x + (float)a.y * (float)b.y;
#endif
}

// ---- stage right row (f16 channel-pair packed) into sP, left column into la2 ----
__device__ __forceinline__ void stage_lr(
    const float* __restrict__ left, const float* __restrict__ right,
    unsigned int* sP, int w, int row, v2h la2[C2])
{
    if (w < 128) {                                 // zero pads
        const int r = w >> 3;
        const int j = w & 7;
        const int idx = (j < 4) ? j : (256 + j);
        sP[r * PP + idx] = 0u;
    }
    #pragma unroll
    for (int i = 0; i < 4; ++i) {                  // 16 rows x 64 float4 groups
        const int g = w + 256 * i;
        const int c2 = g >> 6;
        const int x = (g & 63) << 2;
        const float4 a = *(const float4*)&right[(2 * c2)     * HW + row + x];
        const float4 b = *(const float4*)&right[(2 * c2 + 1) * HW + row + x];
        const v2h h0 = {(_Float16)a.x, (_Float16)b.x};
        const v2h h1 = {(_Float16)a.y, (_Float16)b.y};
        const v2h h2 = {(_Float16)a.z, (_Float16)b.z};
        const v2h h3 = {(_Float16)a.w, (_Float16)b.w};
        uint4 pk;
        pk.x = __builtin_bit_cast(unsigned int, h0);
        pk.y = __builtin_bit_cast(unsigned int, h1);
        pk.z = __builtin_bit_cast(unsigned int, h2);
        pk.w = __builtin_bit_cast(unsigned int, h3);
        *(uint4*)&sP[c2 * PP + 4 + x] = pk;
    }
    #pragma unroll
    for (int k = 0; k < C2; ++k) {
        const float l0 = left[(2 * k)     * HW + row + w];
        const float l1 = left[(2 * k + 1) * HW + row + w];
        la2[k] = {(_Float16)l0, (_Float16)l1};
    }
}

// ---- build this block's k-slice of the banded cost volume ----
__device__ __forceinline__ void build_cv(
    const unsigned int* __restrict__ sP, const v2h la2[C2],
    _Float16* __restrict__ cvg, int w, int row, int by)
{
    const int kb = KPB * by;
    #pragma unroll
    for (int kp = 0; kp < KPB; kp += 2) {
        const int k = kb + kp;
        if (k < KD) {
            const int xr = w - KOFF + k;           // CV for xr (k) and xr+1 (k+1)
            float d0 = 0.f, d1 = 0.f;
            if (xr >= -4 && xr <= 258) {           // sP pads are zero -> masks free
                uint2 u[C2];
                const unsigned int* p = &sP[4 + xr];
                #pragma unroll
                for (int c2 = 0; c2 < C2; ++c2) {
                    u[c2].x = p[0];
                    u[c2].y = p[1];                // adjacent -> ds_read2_b32
                    p += PP;
                }
                #pragma unroll
                for (int c2 = 0; c2 < C2; ++c2) {
                    d0 = fdot2_acc(la2[c2], __builtin_bit_cast(v2h, u[c2].x), d0);
                    d1 = fdot2_acc(la2[c2], __builtin_bit_cast(v2h, u[c2].y), d1);
                }
            }
            const v2h hv = {(_Float16)d0, (_Float16)d1};
            *(unsigned int*)&cvg[(row + w) * KD + k] =    // k even -> 4B aligned
                __builtin_bit_cast(unsigned int, hv);
        }
    }
}

// ---- one softmax-eval from the cost volume (2 f16 loads per tap) ----
__device__ __forceinline__ void eval_cv(
    const _Float16* __restrict__ cvp, int w, float imin, float sc,
    const float np[3], float& ds_out, float& dn_out)
{
    float dsamp[3], frac[3], c0[3], c1[3];
    #pragma unroll
    for (int c = 0; c < 3; ++c) {
        const float disp = fmaf(np[c], sc, imin);
        dsamp[c] = disp;
        const float xs = (float)w - disp;
        const float x0f = floorf(xs);
        frac[c] = xs - x0f;
        int k0 = (int)x0f - w + KOFF;              // analysis: in [4,76]
        k0 = k0 < 0 ? 0 : (k0 > KD - 2 ? KD - 2 : k0);
        c0[c] = (float)cvp[k0];
        c1[c] = (float)cvp[k0 + 1];
    }
    float cost[3];
    #pragma unroll
    for (int c = 0; c < 3; ++c)
        cost[c] = ((1.0f - frac[c]) * c0[c] + frac[c] * c1[c]) * TEMP_OVER_C;
    const float m = fmaxf(cost[0], fmaxf(cost[1], cost[2]));
    const float e0 = __expf(cost[0] - m);
    const float e1 = __expf(cost[1] - m);
    const float e2 = __expf(cost[2] - m);
    const float inv = 1.0f / (e0 + e1 + e2);
    ds_out = (e0 * dsamp[0] + e1 * dsamp[1] + e2 * dsamp[2]) * inv;
    dn_out = (e0 * np[0] + e1 * np[1] + e2 * np[2]) * inv;
}

__device__ __forceinline__ void range_state(
    const float* __restrict__ min_disp, const float* __restrict__ max_disp,
    int row, int w, int s0, float& sc, float imin[SG])
{
    const float mind = fmaxf(min_disp[row + w], 0.0f);
    const float maxd = fmaxf(max_disp[row + w], 0.0f);
    sc = (maxd - mind) * INTERVAL;
    #pragma unroll
    for (int si = 0; si < SG; ++si)
        imin[si] = fmaf(sc, (float)(s0 + si + 1), mind);
}

__global__ __launch_bounds__(256, 3) void pm_fused(
    const float* __restrict__ left,
    const float* __restrict__ right,
    const float* __restrict__ min_disp,
    const float* __restrict__ max_disp,
    const float* __restrict__ noise_in,
    float* __restrict__ nbuf0,
    float* __restrict__ nbuf1,
    _Float16* __restrict__ cvg,
    float* __restrict__ disp_out)
{
    __shared__ unsigned int sP[C2 * PP];   // 16.9 KB
    __shared__ float sN[SG * NPITCH];      // 2.1 KB

    const int w  = threadIdx.x;
    const int h  = blockIdx.x;             // fastest -> XCD locality
    const int by = blockIdx.y;
    const int s0 = SG * by;
    const int row = h * W;

    v2h la2[C2];
    stage_lr(left, right, sP, w, row, la2);
    float sc, imin[SG];
    range_state(min_disp, max_disp, row, w, s0, sc, imin);
    if (w < 2 * SG)
        sN[(w >> 1) * NPITCH + (w & 1) * (NPITCH - 1)] = 0.0f;
    __syncthreads();

    build_cv(sP, la2, cvg, w, row, by);

    cg::grid_group grid = cg::this_grid();
    grid.sync();                           // CV complete

    const _Float16* cvp = cvg + (row + w) * KD;
    float np[3], ds, dn;

    // ---- round 0: horizontal, noise_in -> nbuf0 ----
    #pragma unroll
    for (int si = 0; si < SG; ++si) {
        const int s = s0 + si;
        #pragma unroll
        for (int c = 0; c < 3; ++c) {
            const int x = w + c - 1;
            np[c] = (x >= 0 && x < W) ? noise_in[s * HW + row + x] : 0.0f;
        }
        eval_cv(cvp, w, imin[si], sc, np, ds, dn);
        nbuf0[s * HW + row + w] = dn;
    }

    grid.sync();

    // ---- round 1: vertical, nbuf0 -> sN (LDS only) ----
    #pragma unroll
    for (int si = 0; si < SG; ++si) {
        const int s = s0 + si;
        #pragma unroll
        for (int c = 0; c < 3; ++c) {
            const int y = h + c - 1;
            np[c] = (y >= 0 && y < H) ? nbuf0[s * HW + y * W + w] : 0.0f;
        }
        eval_cv(cvp, w, imin[si], sc, np, ds, dn);
        sN[si * NPITCH + 1 + w] = dn;
    }

    __syncthreads();

    // ---- round 2: horizontal, sN -> nbuf1 ----
    #pragma unroll
    for (int si = 0; si < SG; ++si) {
        const int s = s0 + si;
        #pragma unroll
        for (int c = 0; c < 3; ++c)
            np[c] = sN[si * NPITCH + w + c];   // pads give 0 at edges
        eval_cv(cvp, w, imin[si], sc, np, ds, dn);
        nbuf1[s * HW + row + w] = dn;
    }

    grid.sync();

    // ---- round 3: vertical, nbuf1 -> disp_out ----
    #pragma unroll
    for (int si = 0; si < SG; ++si) {
        const int s = s0 + si;
        #pragma unroll
        for (int c = 0; c < 3; ++c) {
            const int y = h + c - 1;
            np[c] = (y >= 0 && y < H) ? nbuf1[s * HW + y * W + w] : 0.0f;
        }
        eval_cv(cvp, w, imin[si], sc, np, ds, dn);
        disp_out[s * HW + row + w] = ds;
    }
}

// ---------------- fallback: 4-kernel split (identical math) ----------------
__global__ __launch_bounds__(256, 3) void pm_cv(
    const float* __restrict__ left, const float* __restrict__ right,
    _Float16* __restrict__ cvg)
{
    __shared__ unsigned int sP[C2 * PP];
    const int w = threadIdx.x, h = blockIdx.x, by = blockIdx.y;
    const int row = h * W;
    v2h la2[C2];
    stage_lr(left, right, sP, w, row, la2);
    __syncthreads();
    build_cv(sP, la2, cvg, w, row, by);
}

// PHASE 0: r0 horizontal (noise_in) -> nout
// PHASE 1: r1 vertical (nin) -> LDS -> r2 horizontal -> nout
// PHASE 2: r3 vertical (nin) -> ds -> nout
template <int PHASE>
__global__ __launch_bounds__(256, 3) void pm_part(
    const float* __restrict__ min_disp, const float* __restrict__ max_disp,
    const _Float16* __restrict__ cvg,
    const float* __restrict__ nin, float* __restrict__ nout)
{
    __shared__ float sN[SG * NPITCH];
    const int w = threadIdx.x, h = blockIdx.x;
    const int s0 = SG * blockIdx.y;
    const int row = h * W;

    float sc, imin[SG];
    range_state(min_disp, max_disp, row, w, s0, sc, imin);
    if (PHASE == 1 && w < 2 * SG)
        sN[(w >> 1) * NPITCH + (w & 1) * (NPITCH - 1)] = 0.0f;
    if (PHASE == 1) __syncthreads();

    const _Float16* cvp = cvg + (row + w) * KD;
    float np[3], ds, dn;
    #pragma unroll
    for (int si = 0; si < SG; ++si) {
        const int s = s0 + si;
        #pragma unroll
        for (int c = 0; c < 3; ++c) {
            if (PHASE == 0) {
                const int x = w + c - 1;
                np[c] = (x >= 0 && x < W) ? nin[s * HW + row + x] : 0.0f;
            } else {
                const int y = h + c - 1;
                np[c] = (y >= 0 && y < H) ? nin[s * HW + y * W + w] : 0.0f;
            }
        }
        eval_cv(cvp, w, imin[si], sc, np, ds, dn);
        if (PHASE == 1) sN[si * NPITCH + 1 + w] = dn;
        else            nout[s * HW + row + w] = (PHASE == 2) ? ds : dn;
    }

    if (PHASE == 1) {
        __syncthreads();
        #pragma unroll
        for (int si = 0; si < SG; ++si) {
            const int s = s0 + si;
            #pragma unroll
            for (int c = 0; c < 3; ++c)
                np[c] = sN[si * NPITCH + w + c];
            eval_cv(cvp, w, imin[si], sc, np, ds, dn);
            nout[s * HW + row + w] = dn;
        }
    }
}

extern "C" void kernel_launch(void* const* d_in, const int* in_sizes, int n_in,
                              void* d_out, int out_size, void* d_ws, size_t ws_size,
                              hipStream_t stream) {
    const float* left  = (const float*)d_in[0];
    const float* right = (const float*)d_in[1];
    const float* mind  = (const float*)d_in[2];
    const float* maxd  = (const float*)d_in[3];
    const float* noise = (const float*)d_in[4];
    float* out   = (float*)d_out;
    float* nbuf0 = (float*)d_ws;               // S*H*W floats = 1.5 MB
    float* nbuf1 = nbuf0 + S * HW;             // 1.5 MB
    _Float16* cvg = (_Float16*)(nbuf1 + S * HW);   // H*W*KD halves = 5.2 MB

    dim3 grid(H, GY);    // 128 x 6 = 768 blocks; 3 blocks/CU guaranteed
    dim3 block(256);

    void* args[] = {
        (void*)&left, (void*)&right, (void*)&mind, (void*)&maxd,
        (void*)&noise, (void*)&nbuf0, (void*)&nbuf1, (void*)&cvg, (void*)&out
    };
    hipError_t err = hipLaunchCooperativeKernel(
        (const void*)pm_fused, grid, block, args, 0, stream);
    if (err != hipSuccess) {
        (void)hipGetLastError();   // clear error state, use split path
        pm_cv<<<grid, block, 0, stream>>>(left, right, cvg);
        pm_part<0><<<grid, block, 0, stream>>>(mind, maxd, cvg, noise, nbuf0);
        pm_part<1><<<grid, block, 0, stream>>>(mind, maxd, cvg, nbuf0, nbuf1);
        pm_part<2><<<grid, block, 0, stream>>>(mind, maxd, cvg, nbuf1, out);
    }
}

// Round 9
// 93.028 us; speedup vs baseline: 3.7703x; 3.7703x over previous
//
#include <hip/hip_runtime.h>

// PatchMatch stereo — MI355X (gfx950), R8: NO cooperative launch.
// Finding from R3–R7: grid.sync() costs ~60-100us each on 8-XCD MI355X;
// plain graph-captured launches cost ~5-10us. So: 4 stream-ordered kernels.
//   1) pm_build: banded cost volume CV[k][pixel] via f16 MFMA GEMM
//      (CV[px][xr] = sum_c L[c][px]*R[c][xr], K=32 = ONE mfma_f32_16x16x32_f16)
//   2) pm_part<0>: round 0 (horizontal taps) -> nbuf0
//   3) pm_part<1>: round 1 (vertical) -> LDS -> round 2 (horizontal) -> nbuf1
//   4) pm_part<2>: round 3 (vertical) -> disp -> d_out
// Eval per tap = 2 f16 loads from CV + lerp (noise-independent dots hoisted).
// CV k-major so lanes sharing k0 coalesce. Band k = xr-px+76 in [0,80);
// out-of-range xr staged as zero -> matches reference's v0/v1 masks.

namespace {
constexpr int C = 32;
constexpr int H = 128;
constexpr int W = 256;
constexpr int S = 12;
constexpr int HW = H * W;
constexpr int KD = 80;                // band width
constexpr int KOFF = 76;              // k = xr - px + KOFF
constexpr int RT = 144;               // staged xr values per build block
constexpr int CMP = RT + 1;           // 145 (odd) -> conflict-free transpose
constexpr int NPITCH = W + 2;
constexpr float TEMP_OVER_C = 7.0f / 32.0f;
constexpr float INTERVAL = 1.0f / (S + 1);

typedef _Float16 v2h __attribute__((ext_vector_type(2)));
typedef _Float16 v8h __attribute__((ext_vector_type(8)));
typedef float    v4f __attribute__((ext_vector_type(4)));
}

// ---------------- CV build: f16 MFMA GEMM band, one row slice per block ----
// grid (H, 4), block 256 = 4 waves. Block covers 64 px (w0B = 64*blockIdx.y);
// each wave one 16-px tile, 6 MFMAs sweep xr offsets covering k in [0,80).
__global__ __launch_bounds__(256, 2) void pm_build(
    const float* __restrict__ left, const float* __restrict__ right,
    _Float16* __restrict__ cvg)
{
    __shared__ unsigned int cm[16 * CMP];   // [c2][xo] f16-pair dwords, 9.3 KB
    __shared__ unsigned int rt[RT * 16];    // [xo][c2] transposed,       9.2 KB

    const int tid  = threadIdx.x;
    const int lane = tid & 63, wid = tid >> 6;
    const int q = lane >> 4, n = lane & 15;
    const int h = blockIdx.x, row = h * W;      // h fastest -> XCD locality
    const int w0B = 64 * blockIdx.y;
    const int w0w = w0B + 16 * wid;

    // pass A: global (x-coalesced) -> cm[c2][xo]; xr = w0B - KOFF + xo
    #pragma unroll
    for (int i = 0; i < 9; ++i) {               // 16*144 = 2304 dwords
        const int idx = tid + 256 * i;
        const int c2 = idx / RT;
        const int xo = idx - c2 * RT;
        const int x = w0B - KOFF + xo;
        float r0 = 0.f, r1 = 0.f;
        if ((unsigned)x < (unsigned)W) {
            r0 = right[(2 * c2)     * HW + row + x];
            r1 = right[(2 * c2 + 1) * HW + row + x];
        }
        const v2h pr = {(_Float16)r0, (_Float16)r1};
        cm[c2 * CMP + xo] = __builtin_bit_cast(unsigned int, pr);
    }
    __syncthreads();
    // pass B: transpose -> rt[xo][c2] (odd cm pitch => <=4-way, writes free)
    #pragma unroll
    for (int i = 0; i < 9; ++i) {
        const int idx = tid + 256 * i;
        const int c2 = idx & 15;
        const int xo = idx >> 4;
        rt[xo * 16 + c2] = cm[c2 * CMP + xo];
    }

    // A fragment: lane holds L[ch = q*8+j][px = w0w + n]  (4 x 64B segments)
    v8h a;
    #pragma unroll
    for (int j = 0; j < 8; ++j)
        a[j] = (_Float16)left[(q * 8 + j) * HW + row + w0w + n];

    __syncthreads();

    #pragma unroll
    for (int t = 0; t < 6; ++t) {
        // B fragment: lane holds R[ch = q*8+j][xr = x0t + n], one b128
        const uint4 braw = *(const uint4*)&rt[(16 * (wid + t) + n) * 16 + q * 4];
        const v8h b = __builtin_bit_cast(v8h, braw);
        v4f d = {0.f, 0.f, 0.f, 0.f};
        d = __builtin_amdgcn_mfma_f32_16x16x32_f16(a, b, d, 0, 0, 0);
        // D: lane holds D[m = q*4+r][n], m = local px, n = local xr
        #pragma unroll
        for (int r = 0; r < 4; ++r) {
            const int m = q * 4 + r;
            const int k = 16 * t + n - m;       // = xr - px + KOFF
            if (k >= 0 && k < KD)
                cvg[k * HW + row + w0w + m] = (_Float16)d[r];
        }
    }
}

// ---------------- rounds: eval from CV (2 f16 loads + lerp per tap) --------
__device__ __forceinline__ void eval_cv(
    const _Float16* __restrict__ cvg, int row, int w,
    float imin, float sc, const float np[3], float& ds_out, float& dn_out)
{
    float dsamp[3], cost[3];
    #pragma unroll
    for (int c = 0; c < 3; ++c) {
        const float disp = fmaf(np[c], sc, imin);
        dsamp[c] = disp;
        const float xs = (float)w - disp;
        const float x0f = floorf(xs);
        const float fr = xs - x0f;
        int k0 = (int)x0f - w + KOFF;           // analysis: in [4,76]
        k0 = k0 < 0 ? 0 : (k0 > KD - 2 ? KD - 2 : k0);
        const float c0 = (float)cvg[k0 * HW + row + w];
        const float c1 = (float)cvg[(k0 + 1) * HW + row + w];
        cost[c] = ((1.0f - fr) * c0 + fr * c1) * TEMP_OVER_C;
    }
    const float m = fmaxf(cost[0], fmaxf(cost[1], cost[2]));
    const float e0 = __expf(cost[0] - m);
    const float e1 = __expf(cost[1] - m);
    const float e2 = __expf(cost[2] - m);
    const float inv = 1.0f / (e0 + e1 + e2);
    ds_out = (e0 * dsamp[0] + e1 * dsamp[1] + e2 * dsamp[2]) * inv;
    dn_out = (e0 * np[0] + e1 * np[1] + e2 * np[2]) * inv;
}

// PHASE 0: round 0 horizontal (noise_in) -> nout
// PHASE 1: round 1 vertical (nin) -> LDS -> round 2 horizontal -> nout
// PHASE 2: round 3 vertical (nin) -> ds -> nout
template <int PHASE>
__global__ __launch_bounds__(256, 2) void pm_part(
    const float* __restrict__ min_disp, const float* __restrict__ max_disp,
    const _Float16* __restrict__ cvg,
    const float* __restrict__ nin, float* __restrict__ nout)
{
    __shared__ float sN[NPITCH];

    const int w = threadIdx.x;
    const int h = blockIdx.x;                   // fastest -> XCD locality
    const int s = blockIdx.y;
    const int row = h * W;

    const float mind = fmaxf(min_disp[row + w], 0.0f);
    const float maxd = fmaxf(max_disp[row + w], 0.0f);
    const float sc = (maxd - mind) * INTERVAL;
    const float imin = fmaf(sc, (float)(s + 1), mind);

    if (PHASE == 1 && w < 2)
        sN[w * (NPITCH - 1)] = 0.0f;            // pads 0 and 257 stay zero

    float np[3], ds, dn;
    #pragma unroll
    for (int c = 0; c < 3; ++c) {
        if (PHASE == 0) {
            const int x = w + c - 1;
            np[c] = (x >= 0 && x < W) ? nin[s * HW + row + x] : 0.0f;
        } else {
            const int y = h + c - 1;
            np[c] = (y >= 0 && y < H) ? nin[s * HW + y * W + w] : 0.0f;
        }
    }
    eval_cv(cvg, row, w, imin, sc, np, ds, dn);

    if (PHASE == 1) {
        __syncthreads();                        // pads written
        sN[1 + w] = dn;
        __syncthreads();
        #pragma unroll
        for (int c = 0; c < 3; ++c)
            np[c] = sN[w + c];                  // pads give 0 at edges
        eval_cv(cvg, row, w, imin, sc, np, ds, dn);
        nout[s * HW + row + w] = dn;
    } else {
        nout[s * HW + row + w] = (PHASE == 2) ? ds : dn;
    }
}

extern "C" void kernel_launch(void* const* d_in, const int* in_sizes, int n_in,
                              void* d_out, int out_size, void* d_ws, size_t ws_size,
                              hipStream_t stream) {
    const float* left  = (const float*)d_in[0];
    const float* right = (const float*)d_in[1];
    const float* mind  = (const float*)d_in[2];
    const float* maxd  = (const float*)d_in[3];
    const float* noise = (const float*)d_in[4];
    float* out   = (float*)d_out;
    float* nbuf0 = (float*)d_ws;                   // S*H*W f32 = 1.5 MB
    float* nbuf1 = nbuf0 + S * HW;                 // 1.5 MB
    _Float16* cvg = (_Float16*)(nbuf1 + S * HW);   // KD*H*W f16 = 5.24 MB

    dim3 block(256);
    pm_build<<<dim3(H, 4), block, 0, stream>>>(left, right, cvg);
    pm_part<0><<<dim3(H, S), block, 0, stream>>>(mind, maxd, cvg, noise, nbuf0);
    pm_part<1><<<dim3(H, S), block, 0, stream>>>(mind, maxd, cvg, nbuf0, nbuf1);
    pm_part<2><<<dim3(H, S), block, 0, stream>>>(mind, maxd, cvg, nbuf1, out);
}

// Round 10
// 90.391 us; speedup vs baseline: 3.8803x; 1.0292x over previous
//
#include <hip/hip_runtime.h>

// PatchMatch stereo — MI355X (gfx950), R9: 3 stream-ordered kernels.
// Lessons: grid.sync() ~60-100us on 8 XCDs (R3-R7) -> plain launches win;
// noise-independent channel dots hoisted into a banded cost volume built
// with f16 MFMA (R8, 93us). R9: fuse round 0 into the build kernel — eval
// only ever reads its OWN pixel's CV band, which the build block holds in
// LDS. Saves one launch + round-0's global CV reads. Structure:
//   1) pm_build_r0: CV band via mfma_f32_16x16x32_f16 (64 px/block, LDS
//      tile sCV[80][64]) + round 0 (horizontal) from sCV -> nbuf0, CV -> ws
//   2) pm_part<1>: round 1 (vertical, nbuf0) -> LDS -> round 2 (horiz) -> nbuf1
//   3) pm_part<2>: round 3 (vertical, nbuf1) -> disp -> d_out
// Vertical propagation forces the two remaining kernel boundaries: 3 is
// the structural minimum without grid.sync.

namespace {
constexpr int C = 32;
constexpr int H = 128;
constexpr int W = 256;
constexpr int S = 12;
constexpr int HW = H * W;
constexpr int KD = 80;                // band width; k = xr - px + KOFF
constexpr int KOFF = 76;
constexpr int RT = 144;               // staged xr values per build block
constexpr int CMP = RT + 1;           // odd pitch -> conflict-free transpose
constexpr int NPITCH = W + 2;
constexpr float TEMP_OVER_C = 7.0f / 32.0f;
constexpr float INTERVAL = 1.0f / (S + 1);

typedef _Float16 v2h __attribute__((ext_vector_type(2)));
typedef _Float16 v8h __attribute__((ext_vector_type(8)));
typedef float    v4f __attribute__((ext_vector_type(4)));
}

// ---- shared eval: CV band at stride (global: HW / LDS: 64), 3 taps -------
__device__ __forceinline__ void eval_band(
    const _Float16* __restrict__ cvb, int stride, int w,
    float imin, float sc, const float np[3], float& ds_out, float& dn_out)
{
    float dsamp[3], cost[3];
    #pragma unroll
    for (int c = 0; c < 3; ++c) {
        const float disp = fmaf(np[c], sc, imin);
        dsamp[c] = disp;
        const float xs = (float)w - disp;
        const float x0f = floorf(xs);
        const float fr = xs - x0f;
        int k0 = (int)x0f - w + KOFF;           // analysis: in [4,76]
        k0 = k0 < 0 ? 0 : (k0 > KD - 2 ? KD - 2 : k0);
        const float c0 = (float)cvb[k0 * stride];
        const float c1 = (float)cvb[(k0 + 1) * stride];
        cost[c] = ((1.0f - fr) * c0 + fr * c1) * TEMP_OVER_C;
    }
    const float m = fmaxf(cost[0], fmaxf(cost[1], cost[2]));
    const float e0 = __expf(cost[0] - m);
    const float e1 = __expf(cost[1] - m);
    const float e2 = __expf(cost[2] - m);
    const float inv = 1.0f / (e0 + e1 + e2);
    ds_out = (e0 * dsamp[0] + e1 * dsamp[1] + e2 * dsamp[2]) * inv;
    dn_out = (e0 * np[0] + e1 * np[1] + e2 * np[2]) * inv;
}

// ---------------- kernel 1: CV build (MFMA) + round 0 ---------------------
// grid (H, 4), block 256 = 4 waves; block covers 64 px (w0B = 64*blockIdx.y).
__global__ __launch_bounds__(256, 2) void pm_build_r0(
    const float* __restrict__ left, const float* __restrict__ right,
    const float* __restrict__ min_disp, const float* __restrict__ max_disp,
    const float* __restrict__ noise_in,
    _Float16* __restrict__ cvg, float* __restrict__ nbuf0)
{
    __shared__ unsigned int cm[16 * CMP];   // [c2][xo] f16-pair dwords, 9.3 KB
    __shared__ unsigned int rt[RT * 16];    // [xo][c2] transposed,       9.2 KB
    __shared__ _Float16 sCV[KD * 64];       // [k][local px],            10.2 KB

    const int tid  = threadIdx.x;
    const int lane = tid & 63, wid = tid >> 6;
    const int q = lane >> 4, n = lane & 15;
    const int h = blockIdx.x, row = h * W;      // h fastest -> XCD locality
    const int w0B = 64 * blockIdx.y;
    const int w0w = w0B + 16 * wid;

    // pass A: global (x-coalesced) -> cm[c2][xo]; xr = w0B - KOFF + xo
    #pragma unroll
    for (int i = 0; i < 9; ++i) {               // 16*144 = 2304 dwords
        const int idx = tid + 256 * i;
        const int c2 = idx / RT;
        const int xo = idx - c2 * RT;
        const int x = w0B - KOFF + xo;
        float r0 = 0.f, r1 = 0.f;
        if ((unsigned)x < (unsigned)W) {
            r0 = right[(2 * c2)     * HW + row + x];
            r1 = right[(2 * c2 + 1) * HW + row + x];
        }
        const v2h pr = {(_Float16)r0, (_Float16)r1};
        cm[c2 * CMP + xo] = __builtin_bit_cast(unsigned int, pr);
    }
    __syncthreads();
    // pass B: transpose -> rt[xo][c2]
    #pragma unroll
    for (int i = 0; i < 9; ++i) {
        const int idx = tid + 256 * i;
        const int c2 = idx & 15;
        const int xo = idx >> 4;
        rt[xo * 16 + c2] = cm[c2 * CMP + xo];
    }

    // A fragment: lane holds L[ch = q*8+j][px = w0w + n]
    v8h a;
    #pragma unroll
    for (int j = 0; j < 8; ++j)
        a[j] = (_Float16)left[(q * 8 + j) * HW + row + w0w + n];

    __syncthreads();

    #pragma unroll
    for (int t = 0; t < 6; ++t) {
        const uint4 braw = *(const uint4*)&rt[(16 * (wid + t) + n) * 16 + q * 4];
        const v8h b = __builtin_bit_cast(v8h, braw);
        v4f d = {0.f, 0.f, 0.f, 0.f};
        d = __builtin_amdgcn_mfma_f32_16x16x32_f16(a, b, d, 0, 0, 0);
        // D: lane holds D[m = q*4+r][n];  k = 16t + n - m
        #pragma unroll
        for (int r = 0; r < 4; ++r) {
            const int m = q * 4 + r;
            const int k = 16 * t + n - m;
            if (k >= 0 && k < KD) {
                const _Float16 v = (_Float16)d[r];
                cvg[k * HW + row + w0w + m] = v;       // for kernels 2,3
                sCV[k * 64 + 16 * wid + m] = v;        // for round 0 here
            }
        }
    }
    __syncthreads();

    // ---- round 0 (horizontal) for this block's 64 px x all 12 s ----
    const int px = tid & 63;                    // local pixel
    const int sq = tid >> 6;                    // 0..3
    const int wpx = w0B + px;
    const float mind = fmaxf(min_disp[row + wpx], 0.0f);
    const float maxd = fmaxf(max_disp[row + wpx], 0.0f);
    const float sc = (maxd - mind) * INTERVAL;
    const _Float16* cvb = &sCV[px];

    #pragma unroll
    for (int si = 0; si < 3; ++si) {
        const int s = 3 * sq + si;
        const float imin = fmaf(sc, (float)(s + 1), mind);
        float np[3];
        #pragma unroll
        for (int c = 0; c < 3; ++c) {
            const int x = wpx + c - 1;
            np[c] = (x >= 0 && x < W) ? noise_in[s * HW + row + x] : 0.0f;
        }
        float ds, dn;
        eval_band(cvb, 64, wpx, imin, sc, np, ds, dn);
        nbuf0[s * HW + row + wpx] = dn;
    }
}

// ---------------- kernels 2,3: rounds from global CV ----------------------
// PHASE 1: round 1 vertical (nin) -> LDS -> round 2 horizontal -> nout
// PHASE 2: round 3 vertical (nin) -> ds -> nout
template <int PHASE>
__global__ __launch_bounds__(256, 2) void pm_part(
    const float* __restrict__ min_disp, const float* __restrict__ max_disp,
    const _Float16* __restrict__ cvg,
    const float* __restrict__ nin, float* __restrict__ nout)
{
    __shared__ float sN[NPITCH];

    const int w = threadIdx.x;
    const int h = blockIdx.x;                   // fastest -> XCD locality
    const int s = blockIdx.y;
    const int row = h * W;

    const float mind = fmaxf(min_disp[row + w], 0.0f);
    const float maxd = fmaxf(max_disp[row + w], 0.0f);
    const float sc = (maxd - mind) * INTERVAL;
    const float imin = fmaf(sc, (float)(s + 1), mind);

    if (PHASE == 1 && w < 2)
        sN[w * (NPITCH - 1)] = 0.0f;            // pads 0 and 257 stay zero

    float np[3], ds, dn;
    #pragma unroll
    for (int c = 0; c < 3; ++c) {               // vertical taps
        const int y = h + c - 1;
        np[c] = (y >= 0 && y < H) ? nin[s * HW + y * W + w] : 0.0f;
    }
    eval_band(cvg + row + w, HW, w, imin, sc, np, ds, dn);

    if (PHASE == 1) {
        __syncthreads();                        // pads written
        sN[1 + w] = dn;
        __syncthreads();
        #pragma unroll
        for (int c = 0; c < 3; ++c)
            np[c] = sN[w + c];                  // pads give 0 at edges
        eval_band(cvg + row + w, HW, w, imin, sc, np, ds, dn);
        nout[s * HW + row + w] = dn;
    } else {
        nout[s * HW + row + w] = ds;
    }
}

extern "C" void kernel_launch(void* const* d_in, const int* in_sizes, int n_in,
                              void* d_out, int out_size, void* d_ws, size_t ws_size,
                              hipStream_t stream) {
    const float* left  = (const float*)d_in[0];
    const float* right = (const float*)d_in[1];
    const float* mind  = (const float*)d_in[2];
    const float* maxd  = (const float*)d_in[3];
    const float* noise = (const float*)d_in[4];
    float* out   = (float*)d_out;
    float* nbuf0 = (float*)d_ws;                   // S*H*W f32 = 1.5 MB
    float* nbuf1 = nbuf0 + S * HW;                 // 1.5 MB
    _Float16* cvg = (_Float16*)(nbuf1 + S * HW);   // KD*H*W f16 = 5.24 MB

    dim3 block(256);
    pm_build_r0<<<dim3(H, 4), block, 0, stream>>>(left, right, mind, maxd,
                                                  noise, cvg, nbuf0);
    pm_part<1><<<dim3(H, S), block, 0, stream>>>(mind, maxd, cvg, nbuf0, nbuf1);
    pm_part<2><<<dim3(H, S), block, 0, stream>>>(mind, maxd, cvg, nbuf1, out);
}

// Round 11
// 88.343 us; speedup vs baseline: 3.9702x; 1.0232x over previous
//
#include <hip/hip_runtime.h>

// PatchMatch stereo — MI355X (gfx950), R10: 3 stream-ordered kernels.
// Lessons: grid.sync() ~60-100us on 8 XCDs (R3-R7) -> plain launches;
// noise-independent channel dots hoisted into banded cost volume built via
// f16 MFMA (R8); round 0 fused into build (R9). R10: CV global write is now
// a COALESCED dword dump from the LDS tile (sCV) instead of scattered 2-byte
// stores from the MFMA epilogue (quad lanes differ in k by 1 -> 64KB-apart
// addresses -> up to 64 transactions per store instruction).
// Structure:
//   1) pm_build_r0: CV band (mfma_f32_16x16x32_f16, 64px/block) -> sCV(LDS)
//      -> coalesced dump -> cvg;  round 0 (horizontal) from sCV -> nbuf0
//   2) pm_part<1>: round 1 (vertical, nbuf0) -> LDS -> round 2 (horiz) -> nbuf1
//   3) pm_part<2>: round 3 (vertical, nbuf1) -> disp -> d_out
// Vertical propagation forces the two remaining kernel boundaries.

namespace {
constexpr int C = 32;
constexpr int H = 128;
constexpr int W = 256;
constexpr int S = 12;
constexpr int HW = H * W;
constexpr int KD = 80;                // band width; k = xr - px + KOFF
constexpr int KOFF = 76;
constexpr int RT = 144;               // staged xr values per build block
constexpr int CMP = RT + 1;           // odd pitch -> conflict-free transpose
constexpr int NPITCH = W + 2;
constexpr float TEMP_OVER_C = 7.0f / 32.0f;
constexpr float INTERVAL = 1.0f / (S + 1);

typedef _Float16 v2h __attribute__((ext_vector_type(2)));
typedef _Float16 v8h __attribute__((ext_vector_type(8)));
typedef float    v4f __attribute__((ext_vector_type(4)));
}

// ---- shared eval: CV band at stride (global: HW / LDS: 64), 3 taps -------
__device__ __forceinline__ void eval_band(
    const _Float16* __restrict__ cvb, int stride, int w,
    float imin, float sc, const float np[3], float& ds_out, float& dn_out)
{
    float dsamp[3], cost[3];
    #pragma unroll
    for (int c = 0; c < 3; ++c) {
        const float disp = fmaf(np[c], sc, imin);
        dsamp[c] = disp;
        const float xs = (float)w - disp;
        const float x0f = floorf(xs);
        const float fr = xs - x0f;
        int k0 = (int)x0f - w + KOFF;           // analysis: in [4,76]
        k0 = k0 < 0 ? 0 : (k0 > KD - 2 ? KD - 2 : k0);
        const float c0 = (float)cvb[k0 * stride];
        const float c1 = (float)cvb[(k0 + 1) * stride];
        cost[c] = ((1.0f - fr) * c0 + fr * c1) * TEMP_OVER_C;
    }
    const float m = fmaxf(cost[0], fmaxf(cost[1], cost[2]));
    const float e0 = __expf(cost[0] - m);
    const float e1 = __expf(cost[1] - m);
    const float e2 = __expf(cost[2] - m);
    const float inv = 1.0f / (e0 + e1 + e2);
    ds_out = (e0 * dsamp[0] + e1 * dsamp[1] + e2 * dsamp[2]) * inv;
    dn_out = (e0 * np[0] + e1 * np[1] + e2 * np[2]) * inv;
}

// ---------------- kernel 1: CV build (MFMA) + round 0 ---------------------
// grid (H, 4), block 256 = 4 waves; block covers 64 px (w0B = 64*blockIdx.y).
__global__ __launch_bounds__(256, 2) void pm_build_r0(
    const float* __restrict__ left, const float* __restrict__ right,
    const float* __restrict__ min_disp, const float* __restrict__ max_disp,
    const float* __restrict__ noise_in,
    _Float16* __restrict__ cvg, float* __restrict__ nbuf0)
{
    __shared__ unsigned int cm[16 * CMP];   // [c2][xo] f16-pair dwords, 9.3 KB
    __shared__ unsigned int rt[RT * 16];    // [xo][c2] transposed,       9.2 KB
    __shared__ _Float16 sCV[KD * 64];       // [k][local px],            10.2 KB

    const int tid  = threadIdx.x;
    const int lane = tid & 63, wid = tid >> 6;
    const int q = lane >> 4, n = lane & 15;
    const int h = blockIdx.x, row = h * W;      // h fastest -> XCD locality
    const int w0B = 64 * blockIdx.y;
    const int w0w = w0B + 16 * wid;

    // pass A: global (x-coalesced) -> cm[c2][xo]; xr = w0B - KOFF + xo
    #pragma unroll
    for (int i = 0; i < 9; ++i) {               // 16*144 = 2304 dwords
        const int idx = tid + 256 * i;
        const int c2 = idx / RT;
        const int xo = idx - c2 * RT;
        const int x = w0B - KOFF + xo;
        float r0 = 0.f, r1 = 0.f;
        if ((unsigned)x < (unsigned)W) {
            r0 = right[(2 * c2)     * HW + row + x];
            r1 = right[(2 * c2 + 1) * HW + row + x];
        }
        const v2h pr = {(_Float16)r0, (_Float16)r1};
        cm[c2 * CMP + xo] = __builtin_bit_cast(unsigned int, pr);
    }
    __syncthreads();
    // pass B: transpose -> rt[xo][c2]
    #pragma unroll
    for (int i = 0; i < 9; ++i) {
        const int idx = tid + 256 * i;
        const int c2 = idx & 15;
        const int xo = idx >> 4;
        rt[xo * 16 + c2] = cm[c2 * CMP + xo];
    }

    // A fragment: lane holds L[ch = q*8+j][px = w0w + n]
    v8h a;
    #pragma unroll
    for (int j = 0; j < 8; ++j)
        a[j] = (_Float16)left[(q * 8 + j) * HW + row + w0w + n];

    __syncthreads();

    #pragma unroll
    for (int t = 0; t < 6; ++t) {
        const uint4 braw = *(const uint4*)&rt[(16 * (wid + t) + n) * 16 + q * 4];
        const v8h b = __builtin_bit_cast(v8h, braw);
        v4f d = {0.f, 0.f, 0.f, 0.f};
        d = __builtin_amdgcn_mfma_f32_16x16x32_f16(a, b, d, 0, 0, 0);
        // D: lane holds D[m = q*4+r][n];  k = 16t + n - m
        #pragma unroll
        for (int r = 0; r < 4; ++r) {
            const int m = q * 4 + r;
            const int k = 16 * t + n - m;
            if (k >= 0 && k < KD)
                sCV[k * 64 + 16 * wid + m] = (_Float16)d[r];
        }
    }
    __syncthreads();

    // ---- coalesced CV dump: 80 k-planes x 32 dwords (128B contiguous) ----
    {
        const unsigned int* sCVd = (const unsigned int*)sCV;
        unsigned int* cvd = (unsigned int*)cvg;
        #pragma unroll
        for (int i = 0; i < 10; ++i) {          // 2560 dwords
            const int idx = tid + 256 * i;
            const int k = idx >> 5;
            const int d = idx & 31;
            cvd[((k * HW + row + w0B) >> 1) + d] = sCVd[k * 32 + d];
        }
    }

    // ---- round 0 (horizontal) for this block's 64 px x all 12 s ----
    const int px = tid & 63;                    // local pixel
    const int sq = tid >> 6;                    // 0..3
    const int wpx = w0B + px;
    const float mind = fmaxf(min_disp[row + wpx], 0.0f);
    const float maxd = fmaxf(max_disp[row + wpx], 0.0f);
    const float sc = (maxd - mind) * INTERVAL;
    const _Float16* cvb = &sCV[px];

    #pragma unroll
    for (int si = 0; si < 3; ++si) {
        const int s = 3 * sq + si;
        const float imin = fmaf(sc, (float)(s + 1), mind);
        float np[3];
        #pragma unroll
        for (int c = 0; c < 3; ++c) {
            const int x = wpx + c - 1;
            np[c] = (x >= 0 && x < W) ? noise_in[s * HW + row + x] : 0.0f;
        }
        float ds, dn;
        eval_band(cvb, 64, wpx, imin, sc, np, ds, dn);
        nbuf0[s * HW + row + wpx] = dn;
    }
}

// ---------------- kernels 2,3: rounds from global CV ----------------------
// PHASE 1: round 1 vertical (nin) -> LDS -> round 2 horizontal -> nout
// PHASE 2: round 3 vertical (nin) -> ds -> nout
template <int PHASE>
__global__ __launch_bounds__(256, 2) void pm_part(
    const float* __restrict__ min_disp, const float* __restrict__ max_disp,
    const _Float16* __restrict__ cvg,
    const float* __restrict__ nin, float* __restrict__ nout)
{
    __shared__ float sN[NPITCH];

    const int w = threadIdx.x;
    const int h = blockIdx.x;                   // fastest -> XCD locality
    const int s = blockIdx.y;
    const int row = h * W;

    const float mind = fmaxf(min_disp[row + w], 0.0f);
    const float maxd = fmaxf(max_disp[row + w], 0.0f);
    const float sc = (maxd - mind) * INTERVAL;
    const float imin = fmaf(sc, (float)(s + 1), mind);

    if (PHASE == 1 && w < 2)
        sN[w * (NPITCH - 1)] = 0.0f;            // pads 0 and 257 stay zero

    float np[3], ds, dn;
    #pragma unroll
    for (int c = 0; c < 3; ++c) {               // vertical taps
        const int y = h + c - 1;
        np[c] = (y >= 0 && y < H) ? nin[s * HW + y * W + w] : 0.0f;
    }
    eval_band(cvg + row + w, HW, w, imin, sc, np, ds, dn);

    if (PHASE == 1) {
        __syncthreads();                        // pads written
        sN[1 + w] = dn;
        __syncthreads();
        #pragma unroll
        for (int c = 0; c < 3; ++c)
            np[c] = sN[w + c];                  // pads give 0 at edges
        eval_band(cvg + row + w, HW, w, imin, sc, np, ds, dn);
        nout[s * HW + row + w] = dn;
    } else {
        nout[s * HW + row + w] = ds;
    }
}

extern "C" void kernel_launch(void* const* d_in, const int* in_sizes, int n_in,
                              void* d_out, int out_size, void* d_ws, size_t ws_size,
                              hipStream_t stream) {
    const float* left  = (const float*)d_in[0];
    const float* right = (const float*)d_in[1];
    const float* mind  = (const float*)d_in[2];
    const float* maxd  = (const float*)d_in[3];
    const float* noise = (const float*)d_in[4];
    float* out   = (float*)d_out;
    float* nbuf0 = (float*)d_ws;                   // S*H*W f32 = 1.5 MB
    float* nbuf1 = nbuf0 + S * HW;                 // 1.5 MB
    _Float16* cvg = (_Float16*)(nbuf1 + S * HW);   // KD*H*W f16 = 5.24 MB

    dim3 block(256);
    pm_build_r0<<<dim3(H, 4), block, 0, stream>>>(left, right, mind, maxd,
                                                  noise, cvg, nbuf0);
    pm_part<1><<<dim3(H, S), block, 0, stream>>>(mind, maxd, cvg, nbuf0, nbuf1);
    pm_part<2><<<dim3(H, S), block, 0, stream>>>(mind, maxd, cvg, nbuf1, out);
}

// Round 12
// 85.051 us; speedup vs baseline: 4.1239x; 1.0387x over previous
//
#include <hip/hip_runtime.h>

// PatchMatch stereo — MI355X (gfx950), R11: 3 stream-ordered kernels.
// Lessons: grid.sync() ~60-100us on 8 XCDs -> plain launches (R8);
// noise-independent dots hoisted into banded cost volume via f16 MFMA (R8);
// round 0 fused into build (R9). R11: CV stored PX-MAJOR (cvg[px*80+k]),
// written straight from the MFMA epilogue (16-lane contiguous 32B runs).
// Key bound: noise in [0,1], sc = search/13 < 4.93 => all 3 taps' (k0,k0+1)
// fit an 8-half window whose position depends only on (imin,sc), NOT noise.
// So each round issues ONE 16B window load (4 dwords) right after min/max —
// overlapping the noise-tap loads — and extracts pairs in registers.
// PHASE1 (rounds 1+2) shares a single window for both evals.
//   1) pm_build_r0: CV band (mfma_f32_16x16x32_f16, 64px/block) -> sCV(LDS)
//      + px-major cvg;  round 0 (horizontal) from sCV -> nbuf0
//   2) pm_part<1>: round 1 (vertical, nbuf0) -> LDS -> round 2 (horiz) -> nbuf1
//   3) pm_part<2>: round 3 (vertical, nbuf1) -> disp -> d_out

namespace {
constexpr int C = 32;
constexpr int H = 128;
constexpr int W = 256;
constexpr int S = 12;
constexpr int HW = H * W;
constexpr int KD = 80;                // band width; k = xr - px + KOFF
constexpr int KOFF = 76;
constexpr int RT = 144;               // staged xr values per build block
constexpr int CMP = RT + 1;           // odd pitch -> conflict-free transpose
constexpr int NPITCH = W + 2;
constexpr float TEMP_OVER_C = 7.0f / 32.0f;
constexpr float INTERVAL = 1.0f / (S + 1);

typedef _Float16 v2h __attribute__((ext_vector_type(2)));
typedef _Float16 v8h __attribute__((ext_vector_type(8)));
typedef float    v4f __attribute__((ext_vector_type(4)));
}

// ---- window position for (imin, sc): 8 halves [kb0 .. kb0+7] covers all taps
__device__ __forceinline__ int win_base(float imin, float sc) {
    int kb0 = ((int)floorf(-imin - sc) + KOFF) & ~1;   // even -> 4B aligned
    return kb0 < 0 ? 0 : (kb0 > KD - 8 ? KD - 8 : kb0);
}

// ---- eval from an 8-half register window ---------------------------------
__device__ __forceinline__ void eval_w(
    unsigned int u0, unsigned int u1, unsigned int u2, unsigned int u3,
    int kb0, int w, float imin, float sc, const float np[3],
    float& ds_out, float& dn_out)
{
    const unsigned long long lo = u0 | ((unsigned long long)u1 << 32); // h0..3
    const unsigned long long hi = u2 | ((unsigned long long)u3 << 32); // h4..7
    float dsamp[3], cost[3];
    #pragma unroll
    for (int c = 0; c < 3; ++c) {
        const float disp = fmaf(np[c], sc, imin);
        dsamp[c] = disp;
        const float xs = (float)w - disp;
        const float x0f = floorf(xs);
        const float fr = xs - x0f;
        int idx = ((int)x0f - w + KOFF) - kb0;     // in [0,6] by construction
        idx = idx < 0 ? 0 : (idx > 6 ? 6 : idx);
        unsigned int pair;
        if (idx < 3)       pair = (unsigned int)(lo >> (16 * idx));
        else if (idx == 3) pair = (unsigned int)((lo >> 48) | ((unsigned long long)u2 << 16));
        else               pair = (unsigned int)(hi >> (16 * (idx - 4)));
        const v2h ph = __builtin_bit_cast(v2h, pair);
        cost[c] = ((1.0f - fr) * (float)ph.x + fr * (float)ph.y) * TEMP_OVER_C;
    }
    const float m = fmaxf(cost[0], fmaxf(cost[1], cost[2]));
    const float e0 = __expf(cost[0] - m);
    const float e1 = __expf(cost[1] - m);
    const float e2 = __expf(cost[2] - m);
    const float inv = 1.0f / (e0 + e1 + e2);
    ds_out = (e0 * dsamp[0] + e1 * dsamp[1] + e2 * dsamp[2]) * inv;
    dn_out = (e0 * np[0] + e1 * np[1] + e2 * np[2]) * inv;
}

// ---------------- kernel 1: CV build (MFMA) + round 0 ---------------------
// grid (H, 4), block 256 = 4 waves; block covers 64 px (w0B = 64*blockIdx.y).
__global__ __launch_bounds__(256, 2) void pm_build_r0(
    const float* __restrict__ left, const float* __restrict__ right,
    const float* __restrict__ min_disp, const float* __restrict__ max_disp,
    const float* __restrict__ noise_in,
    _Float16* __restrict__ cvg, float* __restrict__ nbuf0)
{
    __shared__ unsigned int cm[16 * CMP];   // [c2][xo] f16-pair dwords, 9.3 KB
    __shared__ unsigned int rt[RT * 16];    // [xo][c2] transposed,       9.2 KB
    __shared__ _Float16 sCV[KD * 64];       // [k][local px],            10.2 KB

    const int tid  = threadIdx.x;
    const int lane = tid & 63, wid = tid >> 6;
    const int q = lane >> 4, n = lane & 15;
    const int h = blockIdx.x, row = h * W;      // h fastest -> XCD locality
    const int w0B = 64 * blockIdx.y;
    const int w0w = w0B + 16 * wid;

    // pass A: global (x-coalesced) -> cm[c2][xo]; xr = w0B - KOFF + xo
    #pragma unroll
    for (int i = 0; i < 9; ++i) {               // 16*144 = 2304 dwords
        const int idx = tid + 256 * i;
        const int c2 = idx / RT;
        const int xo = idx - c2 * RT;
        const int x = w0B - KOFF + xo;
        float r0 = 0.f, r1 = 0.f;
        if ((unsigned)x < (unsigned)W) {
            r0 = right[(2 * c2)     * HW + row + x];
            r1 = right[(2 * c2 + 1) * HW + row + x];
        }
        const v2h pr = {(_Float16)r0, (_Float16)r1};
        cm[c2 * CMP + xo] = __builtin_bit_cast(unsigned int, pr);
    }
    __syncthreads();
    // pass B: transpose -> rt[xo][c2]
    #pragma unroll
    for (int i = 0; i < 9; ++i) {
        const int idx = tid + 256 * i;
        const int c2 = idx & 15;
        const int xo = idx >> 4;
        rt[xo * 16 + c2] = cm[c2 * CMP + xo];
    }

    // A fragment: lane holds L[ch = q*8+j][px = w0w + n]
    v8h a;
    #pragma unroll
    for (int j = 0; j < 8; ++j)
        a[j] = (_Float16)left[(q * 8 + j) * HW + row + w0w + n];

    __syncthreads();

    #pragma unroll
    for (int t = 0; t < 6; ++t) {
        const uint4 braw = *(const uint4*)&rt[(16 * (wid + t) + n) * 16 + q * 4];
        const v8h b = __builtin_bit_cast(v8h, braw);
        v4f d = {0.f, 0.f, 0.f, 0.f};
        d = __builtin_amdgcn_mfma_f32_16x16x32_f16(a, b, d, 0, 0, 0);
        // D: lane holds D[m = q*4+r][n];  k = 16t + n - m
        #pragma unroll
        for (int r = 0; r < 4; ++r) {
            const int m = q * 4 + r;
            const int k = 16 * t + n - m;
            if (k >= 0 && k < KD) {
                const _Float16 v = (_Float16)d[r];
                sCV[k * 64 + 16 * wid + m] = v;            // for round 0 here
                cvg[(row + w0w + m) * KD + k] = v;         // px-major: 16-lane
            }                                              // contiguous k-runs
        }
    }
    __syncthreads();

    // ---- round 0 (horizontal) for this block's 64 px x all 12 s ----
    const int px = tid & 63;                    // local pixel
    const int sq = tid >> 6;                    // 0..3
    const int wpx = w0B + px;
    const float mind = fmaxf(min_disp[row + wpx], 0.0f);
    const float maxd = fmaxf(max_disp[row + wpx], 0.0f);
    const float sc = (maxd - mind) * INTERVAL;

    #pragma unroll
    for (int si = 0; si < 3; ++si) {
        const int s = 3 * sq + si;
        const float imin = fmaf(sc, (float)(s + 1), mind);
        const int kb0 = win_base(imin, sc);
        // window from LDS (k-major tile): 8 halves, strided reads
        const _Float16* cb = &sCV[px];
        unsigned int uu[4];
        #pragma unroll
        for (int j = 0; j < 4; ++j) {
            const v2h pp = {cb[(kb0 + 2 * j) * 64], cb[(kb0 + 2 * j + 1) * 64]};
            uu[j] = __builtin_bit_cast(unsigned int, pp);
        }
        float np[3];
        #pragma unroll
        for (int c = 0; c < 3; ++c) {
            const int x = wpx + c - 1;
            np[c] = (x >= 0 && x < W) ? noise_in[s * HW + row + x] : 0.0f;
        }
        float ds, dn;
        eval_w(uu[0], uu[1], uu[2], uu[3], kb0, wpx, imin, sc, np, ds, dn);
        nbuf0[s * HW + row + wpx] = dn;
    }
}

// ---------------- kernels 2,3: rounds from px-major global CV -------------
// PHASE 1: round 1 vertical (nin) -> LDS -> round 2 horizontal -> nout
// PHASE 2: round 3 vertical (nin) -> ds -> nout
template <int PHASE>
__global__ __launch_bounds__(256, 2) void pm_part(
    const float* __restrict__ min_disp, const float* __restrict__ max_disp,
    const _Float16* __restrict__ cvg,
    const float* __restrict__ nin, float* __restrict__ nout)
{
    __shared__ float sN[NPITCH];

    const int w = threadIdx.x;
    const int h = blockIdx.x;                   // fastest -> XCD locality
    const int s = blockIdx.y;
    const int row = h * W;

    const float mind = fmaxf(min_disp[row + w], 0.0f);
    const float maxd = fmaxf(max_disp[row + w], 0.0f);
    const float sc = (maxd - mind) * INTERVAL;
    const float imin = fmaf(sc, (float)(s + 1), mind);

    // CV window: depends only on (pixel, s) -> issue BEFORE noise loads,
    // shared by both evals in PHASE 1. 4B-aligned dword loads.
    const int kb0 = win_base(imin, sc);
    const unsigned int* bp =
        (const unsigned int*)(cvg + (row + w) * KD + kb0);
    const unsigned int u0 = bp[0], u1 = bp[1], u2 = bp[2], u3 = bp[3];

    if (PHASE == 1 && w < 2)
        sN[w * (NPITCH - 1)] = 0.0f;            // pads 0 and 257 stay zero

    float np[3], ds, dn;
    #pragma unroll
    for (int c = 0; c < 3; ++c) {               // vertical taps
        const int y = h + c - 1;
        np[c] = (y >= 0 && y < H) ? nin[s * HW + y * W + w] : 0.0f;
    }
    eval_w(u0, u1, u2, u3, kb0, w, imin, sc, np, ds, dn);

    if (PHASE == 1) {
        __syncthreads();                        // pads written
        sN[1 + w] = dn;
        __syncthreads();
        #pragma unroll
        for (int c = 0; c < 3; ++c)
            np[c] = sN[w + c];                  // pads give 0 at edges
        eval_w(u0, u1, u2, u3, kb0, w, imin, sc, np, ds, dn);
        nout[s * HW + row + w] = dn;
    } else {
        nout[s * HW + row + w] = ds;
    }
}

extern "C" void kernel_launch(void* const* d_in, const int* in_sizes, int n_in,
                              void* d_out, int out_size, void* d_ws, size_t ws_size,
                              hipStream_t stream) {
    const float* left  = (const float*)d_in[0];
    const float* right = (const float*)d_in[1];
    const float* mind  = (const float*)d_in[2];
    const float* maxd  = (const float*)d_in[3];
    const float* noise = (const float*)d_in[4];
    float* out   = (float*)d_out;
    float* nbuf0 = (float*)d_ws;                   // S*H*W f32 = 1.5 MB
    float* nbuf1 = nbuf0 + S * HW;                 // 1.5 MB
    _Float16* cvg = (_Float16*)(nbuf1 + S * HW);   // H*W*KD f16 = 5.24 MB

    dim3 block(256);
    pm_build_r0<<<dim3(H, 4), block, 0, stream>>>(left, right, mind, maxd,
                                                  noise, cvg, nbuf0);
    pm_part<1><<<dim3(H, S), block, 0, stream>>>(mind, maxd, cvg, nbuf0, nbuf1);
    pm_part<2><<<dim3(H, S), block, 0, stream>>>(mind, maxd, cvg, nbuf1, out);
}

// Round 13
// 81.361 us; speedup vs baseline: 4.3109x; 1.0454x over previous
//
#include <hip/hip_runtime.h>

// PatchMatch stereo — MI355X (gfx950), R12: 3 stream-ordered kernels.
// Lessons: grid.sync() ~60-100us on 8 XCDs -> plain launches (R8); noise-
// independent dots hoisted into banded cost volume via f16 MFMA (R8); round
// 0 fused into build (R9); per-(px,s) 8-half CV window position depends only
// on (imin,sc), not noise (R11). R12: the cost volume never leaves the build
// block — round 0 extracts each (px,s) window from a px-major LDS tile and
// stores it to wbuf as ONE coalesced uint4 (16B/lane, 1KB/wave contiguous).
// cvg (5.2MB, 160B-stride gathers with ~4x line overfetch) is deleted;
// part kernels load exactly one 16B-aligned dwordx4 per pixel and recompute
// kb0 (identical float ops -> identical result).
//   1) pm_build_r0: CV band (mfma_f32_16x16x32_f16, 64px/block) -> sCVp(LDS)
//      -> windows -> wbuf; round 0 (horizontal) -> nbuf0
//   2) pm_part<1>: round 1 (vertical, nbuf0) -> LDS -> round 2 (horiz) -> nbuf1
//   3) pm_part<2>: round 3 (vertical, nbuf1) -> disp -> d_out

namespace {
constexpr int C = 32;
constexpr int H = 128;
constexpr int W = 256;
constexpr int S = 12;
constexpr int HW = H * W;
constexpr int KD = 80;                // band width; k = xr - px + KOFF
constexpr int KOFF = 76;
constexpr int RT = 144;               // staged xr values per build block
constexpr int CMP = RT + 1;           // odd pitch -> conflict-free transpose
constexpr int CVP = 86;               // sCVp pitch (halves): 43 words, odd ->
                                      // conflict-free strided px reads
constexpr int NPITCH = W + 2;
constexpr float TEMP_OVER_C = 7.0f / 32.0f;
constexpr float INTERVAL = 1.0f / (S + 1);

typedef _Float16 v2h __attribute__((ext_vector_type(2)));
typedef _Float16 v8h __attribute__((ext_vector_type(8)));
typedef float    v4f __attribute__((ext_vector_type(4)));
}

// ---- window position for (imin, sc): 8 halves [kb0 .. kb0+7] covers all taps
__device__ __forceinline__ int win_base(float imin, float sc) {
    int kb0 = ((int)floorf(-imin - sc) + KOFF) & ~1;   // even -> dword aligned
    return kb0 < 0 ? 0 : (kb0 > KD - 8 ? KD - 8 : kb0);
}

// ---- eval from an 8-half register window ---------------------------------
__device__ __forceinline__ void eval_w(
    unsigned int u0, unsigned int u1, unsigned int u2, unsigned int u3,
    int kb0, int w, float imin, float sc, const float np[3],
    float& ds_out, float& dn_out)
{
    const unsigned long long lo = u0 | ((unsigned long long)u1 << 32); // h0..3
    const unsigned long long hi = u2 | ((unsigned long long)u3 << 32); // h4..7
    float dsamp[3], cost[3];
    #pragma unroll
    for (int c = 0; c < 3; ++c) {
        const float disp = fmaf(np[c], sc, imin);
        dsamp[c] = disp;
        const float xs = (float)w - disp;
        const float x0f = floorf(xs);
        const float fr = xs - x0f;
        int idx = ((int)x0f - w + KOFF) - kb0;     // in [0,6] by construction
        idx = idx < 0 ? 0 : (idx > 6 ? 6 : idx);
        unsigned int pair;
        if (idx < 3)       pair = (unsigned int)(lo >> (16 * idx));
        else if (idx == 3) pair = (unsigned int)((lo >> 48) | ((unsigned long long)u2 << 16));
        else               pair = (unsigned int)(hi >> (16 * (idx - 4)));
        const v2h ph = __builtin_bit_cast(v2h, pair);
        cost[c] = ((1.0f - fr) * (float)ph.x + fr * (float)ph.y) * TEMP_OVER_C;
    }
    const float m = fmaxf(cost[0], fmaxf(cost[1], cost[2]));
    const float e0 = __expf(cost[0] - m);
    const float e1 = __expf(cost[1] - m);
    const float e2 = __expf(cost[2] - m);
    const float inv = 1.0f / (e0 + e1 + e2);
    ds_out = (e0 * dsamp[0] + e1 * dsamp[1] + e2 * dsamp[2]) * inv;
    dn_out = (e0 * np[0] + e1 * np[1] + e2 * np[2]) * inv;
}

// ---------------- kernel 1: CV build (MFMA) + round 0 + window export -----
// grid (H, 4), block 256 = 4 waves; block covers 64 px (w0B = 64*blockIdx.y).
__global__ __launch_bounds__(256, 2) void pm_build_r0(
    const float* __restrict__ left, const float* __restrict__ right,
    const float* __restrict__ min_disp, const float* __restrict__ max_disp,
    const float* __restrict__ noise_in,
    uint4* __restrict__ wbuf, float* __restrict__ nbuf0)
{
    __shared__ unsigned int cm[16 * CMP];   // [c2][xo] f16-pair dwords, 9.3 KB
    __shared__ unsigned int rt[RT * 16];    // [xo][c2] transposed,       9.2 KB
    __shared__ _Float16 sCVp[64 * CVP];     // [local px][k], px-major,  11.0 KB

    const int tid  = threadIdx.x;
    const int lane = tid & 63, wid = tid >> 6;
    const int q = lane >> 4, n = lane & 15;
    const int h = blockIdx.x, row = h * W;      // h fastest -> XCD locality
    const int w0B = 64 * blockIdx.y;
    const int w0w = w0B + 16 * wid;

    // pass A: global (x-coalesced) -> cm[c2][xo]; xr = w0B - KOFF + xo
    #pragma unroll
    for (int i = 0; i < 9; ++i) {               // 16*144 = 2304 dwords
        const int idx = tid + 256 * i;
        const int c2 = idx / RT;
        const int xo = idx - c2 * RT;
        const int x = w0B - KOFF + xo;
        float r0 = 0.f, r1 = 0.f;
        if ((unsigned)x < (unsigned)W) {
            r0 = right[(2 * c2)     * HW + row + x];
            r1 = right[(2 * c2 + 1) * HW + row + x];
        }
        const v2h pr = {(_Float16)r0, (_Float16)r1};
        cm[c2 * CMP + xo] = __builtin_bit_cast(unsigned int, pr);
    }
    __syncthreads();
    // pass B: transpose -> rt[xo][c2]
    #pragma unroll
    for (int i = 0; i < 9; ++i) {
        const int idx = tid + 256 * i;
        const int c2 = idx & 15;
        const int xo = idx >> 4;
        rt[xo * 16 + c2] = cm[c2 * CMP + xo];
    }

    // A fragment: lane holds L[ch = q*8+j][px = w0w + n]
    v8h a;
    #pragma unroll
    for (int j = 0; j < 8; ++j)
        a[j] = (_Float16)left[(q * 8 + j) * HW + row + w0w + n];

    __syncthreads();

    #pragma unroll
    for (int t = 0; t < 6; ++t) {
        const uint4 braw = *(const uint4*)&rt[(16 * (wid + t) + n) * 16 + q * 4];
        const v8h b = __builtin_bit_cast(v8h, braw);
        v4f d = {0.f, 0.f, 0.f, 0.f};
        d = __builtin_amdgcn_mfma_f32_16x16x32_f16(a, b, d, 0, 0, 0);
        // D: lane holds D[m = q*4+r][n];  k = 16t + n - m
        #pragma unroll
        for (int r = 0; r < 4; ++r) {
            const int m = q * 4 + r;
            const int k = 16 * t + n - m;
            if (k >= 0 && k < KD)
                sCVp[(16 * wid + m) * CVP + k] = (_Float16)d[r];
        }
    }
    __syncthreads();

    // ---- round 0 (horizontal) + window export, 64 px x all 12 s ----
    const int px = tid & 63;                    // local pixel
    const int sq = tid >> 6;                    // 0..3
    const int wpx = w0B + px;
    const float mind = fmaxf(min_disp[row + wpx], 0.0f);
    const float maxd = fmaxf(max_disp[row + wpx], 0.0f);
    const float sc = (maxd - mind) * INTERVAL;

    #pragma unroll
    for (int si = 0; si < 3; ++si) {
        const int s = 3 * sq + si;
        const float imin = fmaf(sc, (float)(s + 1), mind);
        const int kb0 = win_base(imin, sc);
        // contiguous 4-dword window from px-major LDS (dword aligned: kb0 even)
        const unsigned int* cb = (const unsigned int*)&sCVp[px * CVP + kb0];
        const unsigned int u0 = cb[0], u1 = cb[1], u2 = cb[2], u3 = cb[3];
        wbuf[s * HW + row + wpx] = make_uint4(u0, u1, u2, u3);  // coalesced 16B

        float np[3];
        #pragma unroll
        for (int c = 0; c < 3; ++c) {
            const int x = wpx + c - 1;
            np[c] = (x >= 0 && x < W) ? noise_in[s * HW + row + x] : 0.0f;
        }
        float ds, dn;
        eval_w(u0, u1, u2, u3, kb0, wpx, imin, sc, np, ds, dn);
        nbuf0[s * HW + row + wpx] = dn;
    }
}

// ---------------- kernels 2,3: rounds from extracted windows --------------
// PHASE 1: round 1 vertical (nin) -> LDS -> round 2 horizontal -> nout
// PHASE 2: round 3 vertical (nin) -> ds -> nout
template <int PHASE>
__global__ __launch_bounds__(256, 2) void pm_part(
    const float* __restrict__ min_disp, const float* __restrict__ max_disp,
    const uint4* __restrict__ wbuf,
    const float* __restrict__ nin, float* __restrict__ nout)
{
    __shared__ float sN[NPITCH];

    const int w = threadIdx.x;
    const int h = blockIdx.x;                   // fastest -> XCD locality
    const int s = blockIdx.y;
    const int row = h * W;

    // window load: independent of everything else -> issue first
    const uint4 wb = wbuf[s * HW + row + w];    // one dwordx4, coalesced

    const float mind = fmaxf(min_disp[row + w], 0.0f);
    const float maxd = fmaxf(max_disp[row + w], 0.0f);
    const float sc = (maxd - mind) * INTERVAL;
    const float imin = fmaf(sc, (float)(s + 1), mind);
    const int kb0 = win_base(imin, sc);         // identical ops as build

    if (PHASE == 1 && w < 2)
        sN[w * (NPITCH - 1)] = 0.0f;            // pads 0 and 257 stay zero

    float np[3], ds, dn;
    #pragma unroll
    for (int c = 0; c < 3; ++c) {               // vertical taps
        const int y = h + c - 1;
        np[c] = (y >= 0 && y < H) ? nin[s * HW + y * W + w] : 0.0f;
    }
    eval_w(wb.x, wb.y, wb.z, wb.w, kb0, w, imin, sc, np, ds, dn);

    if (PHASE == 1) {
        sN[1 + w] = dn;                         // disjoint from pads
        __syncthreads();                        // single barrier
        #pragma unroll
        for (int c = 0; c < 3; ++c)
            np[c] = sN[w + c];                  // pads give 0 at edges
        eval_w(wb.x, wb.y, wb.z, wb.w, kb0, w, imin, sc, np, ds, dn);
        nout[s * HW + row + w] = dn;
    } else {
        nout[s * HW + row + w] = ds;
    }
}

extern "C" void kernel_launch(void* const* d_in, const int* in_sizes, int n_in,
                              void* d_out, int out_size, void* d_ws, size_t ws_size,
                              hipStream_t stream) {
    const float* left  = (const float*)d_in[0];
    const float* right = (const float*)d_in[1];
    const float* mind  = (const float*)d_in[2];
    const float* maxd  = (const float*)d_in[3];
    const float* noise = (const float*)d_in[4];
    float* out   = (float*)d_out;
    float* nbuf0 = (float*)d_ws;                   // S*H*W f32 = 1.5 MB
    float* nbuf1 = nbuf0 + S * HW;                 // 1.5 MB
    uint4* wbuf  = (uint4*)(nbuf1 + S * HW);       // S*H*W uint4 = 6.3 MB

    dim3 block(256);
    pm_build_r0<<<dim3(H, 4), block, 0, stream>>>(left, right, mind, maxd,
                                                  noise, wbuf, nbuf0);
    pm_part<1><<<dim3(H, S), block, 0, stream>>>(mind, maxd, wbuf, nbuf0, nbuf1);
    pm_part<2><<<dim3(H, S), block, 0, stream>>>(mind, maxd, wbuf, nbuf1, out);
}

// Round 14
// 78.797 us; speedup vs baseline: 4.4512x; 1.0326x over previous
//
#include <hip/hip_runtime.h>

// PatchMatch stereo — MI355X (gfx950), R13: 3 stream-ordered kernels.
// Lessons: grid.sync() ~60-100us on 8 XCDs -> plain launches (R8); noise-
// independent dots hoisted into banded cost volume via f16 MFMA (R8); round
// 0 fused into build (R9); per-(px,s) 8-half window depends only on
// (imin,sc) -> precomputed windows in wbuf, CV never leaves the block (R12).
// R13: staging pass A vectorized — float4 right-image loads (interior
// unmasked, edges element-masked), 16B-aligned packed stores into cm
// (pitch 148: pass-B reads <=2-way aliased = free). ~4x fewer staging insts.
//   1) pm_build_r0: CV band (mfma_f32_16x16x32_f16, 64px/block) -> sCVp(LDS)
//      -> windows -> wbuf; round 0 (horizontal) -> nbuf0
//   2) pm_part<1>: round 1 (vertical, nbuf0) -> LDS -> round 2 (horiz) -> nbuf1
//   3) pm_part<2>: round 3 (vertical, nbuf1) -> disp -> d_out

namespace {
constexpr int C = 32;
constexpr int H = 128;
constexpr int W = 256;
constexpr int S = 12;
constexpr int HW = H * W;
constexpr int KD = 80;                // band width; k = xr - px + KOFF
constexpr int KOFF = 76;
constexpr int RT = 144;               // staged xr values per build block
constexpr int CMP = 148;              // cm pitch (dwords): 16B-aligned stores;
                                      // pass-B reads <=2-way aliased (free)
constexpr int CVP = 86;               // sCVp pitch (halves), odd word stride
constexpr int NPITCH = W + 2;
constexpr float TEMP_OVER_C = 7.0f / 32.0f;
constexpr float INTERVAL = 1.0f / (S + 1);

typedef _Float16 v2h __attribute__((ext_vector_type(2)));
typedef _Float16 v8h __attribute__((ext_vector_type(8)));
typedef float    v4f __attribute__((ext_vector_type(4)));
}

// ---- window position for (imin, sc): 8 halves [kb0 .. kb0+7] covers all taps
__device__ __forceinline__ int win_base(float imin, float sc) {
    int kb0 = ((int)floorf(-imin - sc) + KOFF) & ~1;   // even -> dword aligned
    return kb0 < 0 ? 0 : (kb0 > KD - 8 ? KD - 8 : kb0);
}

// ---- eval from an 8-half register window ---------------------------------
__device__ __forceinline__ void eval_w(
    unsigned int u0, unsigned int u1, unsigned int u2, unsigned int u3,
    int kb0, int w, float imin, float sc, const float np[3],
    float& ds_out, float& dn_out)
{
    const unsigned long long lo = u0 | ((unsigned long long)u1 << 32); // h0..3
    const unsigned long long hi = u2 | ((unsigned long long)u3 << 32); // h4..7
    float dsamp[3], cost[3];
    #pragma unroll
    for (int c = 0; c < 3; ++c) {
        const float disp = fmaf(np[c], sc, imin);
        dsamp[c] = disp;
        const float xs = (float)w - disp;
        const float x0f = floorf(xs);
        const float fr = xs - x0f;
        int idx = ((int)x0f - w + KOFF) - kb0;     // in [0,6] by construction
        idx = idx < 0 ? 0 : (idx > 6 ? 6 : idx);
        unsigned int pair;
        if (idx < 3)       pair = (unsigned int)(lo >> (16 * idx));
        else if (idx == 3) pair = (unsigned int)((lo >> 48) | ((unsigned long long)u2 << 16));
        else               pair = (unsigned int)(hi >> (16 * (idx - 4)));
        const v2h ph = __builtin_bit_cast(v2h, pair);
        cost[c] = ((1.0f - fr) * (float)ph.x + fr * (float)ph.y) * TEMP_OVER_C;
    }
    const float m = fmaxf(cost[0], fmaxf(cost[1], cost[2]));
    const float e0 = __expf(cost[0] - m);
    const float e1 = __expf(cost[1] - m);
    const float e2 = __expf(cost[2] - m);
    const float inv = 1.0f / (e0 + e1 + e2);
    ds_out = (e0 * dsamp[0] + e1 * dsamp[1] + e2 * dsamp[2]) * inv;
    dn_out = (e0 * np[0] + e1 * np[1] + e2 * np[2]) * inv;
}

// ---------------- kernel 1: CV build (MFMA) + round 0 + window export -----
// grid (H, 4), block 256 = 4 waves; block covers 64 px (w0B = 64*blockIdx.y).
__global__ __launch_bounds__(256, 2) void pm_build_r0(
    const float* __restrict__ left, const float* __restrict__ right,
    const float* __restrict__ min_disp, const float* __restrict__ max_disp,
    const float* __restrict__ noise_in,
    uint4* __restrict__ wbuf, float* __restrict__ nbuf0)
{
    __shared__ unsigned int cm[16 * CMP];   // [c2][xo] f16-pair dwords, 9.5 KB
    __shared__ unsigned int rt[RT * 16];    // [xo][c2] transposed,       9.2 KB
    __shared__ _Float16 sCVp[64 * CVP];     // [local px][k], px-major,  11.0 KB

    const int tid  = threadIdx.x;
    const int lane = tid & 63, wid = tid >> 6;
    const int q = lane >> 4, n = lane & 15;
    const int h = blockIdx.x, row = h * W;      // h fastest -> XCD locality
    const int w0B = 64 * blockIdx.y;
    const int w0w = w0B + 16 * wid;

    // pass A (vectorized): float4 groups -> cm[c2][xo]; xr = w0B - KOFF + xo
    // 16 c2 x 36 groups of 4 xo = 576 groups; mapping keeps lanes on x.
    #pragma unroll
    for (int j = 0; j < 3; ++j) {
        const int idx = tid + 256 * j;          // 0..767
        const int c2 = idx / 48;
        const int xg = idx - 48 * c2;
        if (xg < 36) {
            const int x0 = w0B - KOFF + 4 * xg;
            float4 a = {0.f, 0.f, 0.f, 0.f}, b = {0.f, 0.f, 0.f, 0.f};
            if (x0 >= 0 && x0 <= W - 4) {       // interior: unmasked float4
                a = *(const float4*)&right[(2 * c2)     * HW + row + x0];
                b = *(const float4*)&right[(2 * c2 + 1) * HW + row + x0];
            } else if (x0 >= -3 && x0 <= W - 1) {   // edge: element-masked
                float ae[4] = {0, 0, 0, 0}, be[4] = {0, 0, 0, 0};
                #pragma unroll
                for (int e = 0; e < 4; ++e) {
                    const int x = x0 + e;
                    if ((unsigned)x < (unsigned)W) {
                        ae[e] = right[(2 * c2)     * HW + row + x];
                        be[e] = right[(2 * c2 + 1) * HW + row + x];
                    }
                }
                a = make_float4(ae[0], ae[1], ae[2], ae[3]);
                b = make_float4(be[0], be[1], be[2], be[3]);
            }
            const v2h h0 = {(_Float16)a.x, (_Float16)b.x};
            const v2h h1 = {(_Float16)a.y, (_Float16)b.y};
            const v2h h2 = {(_Float16)a.z, (_Float16)b.z};
            const v2h h3 = {(_Float16)a.w, (_Float16)b.w};
            uint4 pk;
            pk.x = __builtin_bit_cast(unsigned int, h0);
            pk.y = __builtin_bit_cast(unsigned int, h1);
            pk.z = __builtin_bit_cast(unsigned int, h2);
            pk.w = __builtin_bit_cast(unsigned int, h3);
            *(uint4*)&cm[c2 * CMP + 4 * xg] = pk;   // 16B aligned (CMP%4==0)
        }
    }
    __syncthreads();
    // pass B: transpose -> rt[xo][c2]
    #pragma unroll
    for (int i = 0; i < 9; ++i) {
        const int idx = tid + 256 * i;              // 16*144 = 2304 dwords
        const int c2 = idx & 15;
        const int xo = idx >> 4;
        rt[xo * 16 + c2] = cm[c2 * CMP + xo];
    }

    // A fragment: lane holds L[ch = q*8+j][px = w0w + n]
    v8h a;
    #pragma unroll
    for (int j = 0; j < 8; ++j)
        a[j] = (_Float16)left[(q * 8 + j) * HW + row + w0w + n];

    __syncthreads();

    #pragma unroll
    for (int t = 0; t < 6; ++t) {
        const uint4 braw = *(const uint4*)&rt[(16 * (wid + t) + n) * 16 + q * 4];
        const v8h b = __builtin_bit_cast(v8h, braw);
        v4f d = {0.f, 0.f, 0.f, 0.f};
        d = __builtin_amdgcn_mfma_f32_16x16x32_f16(a, b, d, 0, 0, 0);
        // D: lane holds D[m = q*4+r][n];  k = 16t + n - m
        #pragma unroll
        for (int r = 0; r < 4; ++r) {
            const int m = q * 4 + r;
            const int k = 16 * t + n - m;
            if (k >= 0 && k < KD)
                sCVp[(16 * wid + m) * CVP + k] = (_Float16)d[r];
        }
    }
    __syncthreads();

    // ---- round 0 (horizontal) + window export, 64 px x all 12 s ----
    const int px = tid & 63;                    // local pixel
    const int sq = tid >> 6;                    // 0..3
    const int wpx = w0B + px;
    const float mind = fmaxf(min_disp[row + wpx], 0.0f);
    const float maxd = fmaxf(max_disp[row + wpx], 0.0f);
    const float sc = (maxd - mind) * INTERVAL;

    #pragma unroll
    for (int si = 0; si < 3; ++si) {
        const int s = 3 * sq + si;
        const float imin = fmaf(sc, (float)(s + 1), mind);
        const int kb0 = win_base(imin, sc);
        // contiguous 4-dword window from px-major LDS (dword aligned: kb0 even)
        const unsigned int* cb = (const unsigned int*)&sCVp[px * CVP + kb0];
        const unsigned int u0 = cb[0], u1 = cb[1], u2 = cb[2], u3 = cb[3];
        wbuf[s * HW + row + wpx] = make_uint4(u0, u1, u2, u3);  // coalesced 16B

        float np[3];
        #pragma unroll
        for (int c = 0; c < 3; ++c) {
            const int x = wpx + c - 1;
            np[c] = (x >= 0 && x < W) ? noise_in[s * HW + row + x] : 0.0f;
        }
        float ds, dn;
        eval_w(u0, u1, u2, u3, kb0, wpx, imin, sc, np, ds, dn);
        nbuf0[s * HW + row + wpx] = dn;
    }
}

// ---------------- kernels 2,3: rounds from extracted windows --------------
// PHASE 1: round 1 vertical (nin) -> LDS -> round 2 horizontal -> nout
// PHASE 2: round 3 vertical (nin) -> ds -> nout
template <int PHASE>
__global__ __launch_bounds__(256, 2) void pm_part(
    const float* __restrict__ min_disp, const float* __restrict__ max_disp,
    const uint4* __restrict__ wbuf,
    const float* __restrict__ nin, float* __restrict__ nout)
{
    __shared__ float sN[NPITCH];

    const int w = threadIdx.x;
    const int h = blockIdx.x;                   // fastest -> XCD locality
    const int s = blockIdx.y;
    const int row = h * W;

    // window load: address is position-only -> issues immediately
    const uint4 wb = wbuf[s * HW + row + w];    // one dwordx4, coalesced

    const float mind = fmaxf(min_disp[row + w], 0.0f);
    const float maxd = fmaxf(max_disp[row + w], 0.0f);
    const float sc = (maxd - mind) * INTERVAL;
    const float imin = fmaf(sc, (float)(s + 1), mind);
    const int kb0 = win_base(imin, sc);         // identical ops as build

    if (PHASE == 1 && w < 2)
        sN[w * (NPITCH - 1)] = 0.0f;            // pads 0 and 257 stay zero

    float np[3], ds, dn;
    #pragma unroll
    for (int c = 0; c < 3; ++c) {               // vertical taps
        const int y = h + c - 1;
        np[c] = (y >= 0 && y < H) ? nin[s * HW + y * W + w] : 0.0f;
    }
    eval_w(wb.x, wb.y, wb.z, wb.w, kb0, w, imin, sc, np, ds, dn);

    if (PHASE == 1) {
        sN[1 + w] = dn;                         // disjoint from pads
        __syncthreads();                        // single barrier
        #pragma unroll
        for (int c = 0; c < 3; ++c)
            np[c] = sN[w + c];                  // pads give 0 at edges
        eval_w(wb.x, wb.y, wb.z, wb.w, kb0, w, imin, sc, np, ds, dn);
        nout[s * HW + row + w] = dn;
    } else {
        nout[s * HW + row + w] = ds;
    }
}

extern "C" void kernel_launch(void* const* d_in, const int* in_sizes, int n_in,
                              void* d_out, int out_size, void* d_ws, size_t ws_size,
                              hipStream_t stream) {
    const float* left  = (const float*)d_in[0];
    const float* right = (const float*)d_in[1];
    const float* mind  = (const float*)d_in[2];
    const float* maxd  = (const float*)d_in[3];
    const float* noise = (const float*)d_in[4];
    float* out   = (float*)d_out;
    float* nbuf0 = (float*)d_ws;                   // S*H*W f32 = 1.5 MB
    float* nbuf1 = nbuf0 + S * HW;                 // 1.5 MB
    uint4* wbuf  = (uint4*)(nbuf1 + S * HW);       // S*H*W uint4 = 6.3 MB

    dim3 block(256);
    pm_build_r0<<<dim3(H, 4), block, 0, stream>>>(left, right, mind, maxd,
                                                  noise, wbuf, nbuf0);
    pm_part<1><<<dim3(H, S), block, 0, stream>>>(mind, maxd, wbuf, nbuf0, nbuf1);
    pm_part<2><<<dim3(H, S), block, 0, stream>>>(mind, maxd, wbuf, nbuf1, out);
}

// Round 15
// 78.004 us; speedup vs baseline: 4.4964x; 1.0102x over previous
//
#include <hip/hip_runtime.h>

// PatchMatch stereo — MI355X (gfx950), R14: 3 stream-ordered kernels.
// Lessons: grid.sync() ~60-100us on 8 XCDs -> plain launches (R8); noise-
// independent dots hoisted into banded cost volume via f16 MFMA (R8); round
// 0 fused into build (R9); per-(px,s) 8-half window depends only on
// (imin,sc) -> windows precomputed to wbuf, CV never leaves the block (R12);
// staging pass A vectorized (R13). R14: MFMA operands SWAPPED (A=R, B=L;
// both fragments share the lane layout row/col=lane&15, k=quad*8+j) so D is
// transposed: each lane holds 4 CONSECUTIVE xr for one px. Epilogue becomes
// 6 unconditional ds_write_b64 (xr-major tile sCVx[px][xo], pitch 148) vs
// 24 predicated ds_write_b16. Window read = 5 aligned dwords + funnel shift.
//   1) pm_build_r0: CV band -> sCVx(LDS) -> windows -> wbuf; round 0 -> nbuf0
//   2) pm_part<1>: round 1 (vertical, nbuf0) -> LDS -> round 2 (horiz) -> nbuf1
//   3) pm_part<2>: round 3 (vertical, nbuf1) -> disp -> d_out

namespace {
constexpr int C = 32;
constexpr int H = 128;
constexpr int W = 256;
constexpr int S = 12;
constexpr int HW = H * W;
constexpr int KD = 80;                // band width; k = xr - px + KOFF
constexpr int KOFF = 76;
constexpr int RT = 144;               // staged xr values per build block
constexpr int CMP = 148;              // cm pitch (dwords): 16B-aligned stores
constexpr int XP  = 148;              // sCVx pitch (halves): rows 8B-aligned
constexpr int NPITCH = W + 2;
constexpr float TEMP_OVER_C = 7.0f / 32.0f;
constexpr float INTERVAL = 1.0f / (S + 1);

typedef _Float16 v2h __attribute__((ext_vector_type(2)));
typedef _Float16 v8h __attribute__((ext_vector_type(8)));
typedef float    v4f __attribute__((ext_vector_type(4)));
}

// ---- window position for (imin, sc): 8 halves [kb0 .. kb0+7] covers all taps
__device__ __forceinline__ int win_base(float imin, float sc) {
    int kb0 = ((int)floorf(-imin - sc) + KOFF) & ~1;   // even
    return kb0 < 0 ? 0 : (kb0 > KD - 8 ? KD - 8 : kb0);
}

// ---- eval from an 8-half register window ---------------------------------
__device__ __forceinline__ void eval_w(
    unsigned int u0, unsigned int u1, unsigned int u2, unsigned int u3,
    int kb0, int w, float imin, float sc, const float np[3],
    float& ds_out, float& dn_out)
{
    const unsigned long long lo = u0 | ((unsigned long long)u1 << 32); // h0..3
    const unsigned long long hi = u2 | ((unsigned long long)u3 << 32); // h4..7
    float dsamp[3], cost[3];
    #pragma unroll
    for (int c = 0; c < 3; ++c) {
        const float disp = fmaf(np[c], sc, imin);
        dsamp[c] = disp;
        const float xs = (float)w - disp;
        const float x0f = floorf(xs);
        const float fr = xs - x0f;
        int idx = ((int)x0f - w + KOFF) - kb0;     // in [0,6] by construction
        idx = idx < 0 ? 0 : (idx > 6 ? 6 : idx);
        unsigned int pair;
        if (idx < 3)       pair = (unsigned int)(lo >> (16 * idx));
        else if (idx == 3) pair = (unsigned int)((lo >> 48) | ((unsigned long long)u2 << 16));
        else               pair = (unsigned int)(hi >> (16 * (idx - 4)));
        const v2h ph = __builtin_bit_cast(v2h, pair);
        cost[c] = ((1.0f - fr) * (float)ph.x + fr * (float)ph.y) * TEMP_OVER_C;
    }
    const float m = fmaxf(cost[0], fmaxf(cost[1], cost[2]));
    const float e0 = __expf(cost[0] - m);
    const float e1 = __expf(cost[1] - m);
    const float e2 = __expf(cost[2] - m);
    const float inv = 1.0f / (e0 + e1 + e2);
    ds_out = (e0 * dsamp[0] + e1 * dsamp[1] + e2 * dsamp[2]) * inv;
    dn_out = (e0 * np[0] + e1 * np[1] + e2 * np[2]) * inv;
}

// ---------------- kernel 1: CV build (MFMA) + round 0 + window export -----
// grid (H, 4), block 256 = 4 waves; block covers 64 px (w0B = 64*blockIdx.y).
__global__ __launch_bounds__(256, 2) void pm_build_r0(
    const float* __restrict__ left, const float* __restrict__ right,
    const float* __restrict__ min_disp, const float* __restrict__ max_disp,
    const float* __restrict__ noise_in,
    uint4* __restrict__ wbuf, float* __restrict__ nbuf0)
{
    __shared__ unsigned int cm[16 * CMP];   // [c2][xo] f16-pair dwords, 9.5 KB
    __shared__ unsigned int rt[RT * 16];    // [xo][c2] transposed,       9.2 KB
    __shared__ _Float16 sCVx[64 * XP];      // [local px][xo], xr-major, 18.9 KB

    const int tid  = threadIdx.x;
    const int lane = tid & 63, wid = tid >> 6;
    const int q = lane >> 4, n = lane & 15;
    const int h = blockIdx.x, row = h * W;      // h fastest -> XCD locality
    const int w0B = 64 * blockIdx.y;
    const int w0w = w0B + 16 * wid;

    // pass A (vectorized): float4 groups -> cm[c2][xo]; xr = w0B - KOFF + xo
    #pragma unroll
    for (int j = 0; j < 3; ++j) {
        const int idx = tid + 256 * j;          // 0..767
        const int c2 = idx / 48;
        const int xg = idx - 48 * c2;
        if (xg < 36) {
            const int x0 = w0B - KOFF + 4 * xg;
            float4 a = {0.f, 0.f, 0.f, 0.f}, b = {0.f, 0.f, 0.f, 0.f};
            if (x0 >= 0 && x0 <= W - 4) {       // interior: unmasked float4
                a = *(const float4*)&right[(2 * c2)     * HW + row + x0];
                b = *(const float4*)&right[(2 * c2 + 1) * HW + row + x0];
            } else if (x0 >= -3 && x0 <= W - 1) {   // edge: element-masked
                float ae[4] = {0, 0, 0, 0}, be[4] = {0, 0, 0, 0};
                #pragma unroll
                for (int e = 0; e < 4; ++e) {
                    const int x = x0 + e;
                    if ((unsigned)x < (unsigned)W) {
                        ae[e] = right[(2 * c2)     * HW + row + x];
                        be[e] = right[(2 * c2 + 1) * HW + row + x];
                    }
                }
                a = make_float4(ae[0], ae[1], ae[2], ae[3]);
                b = make_float4(be[0], be[1], be[2], be[3]);
            }
            const v2h h0 = {(_Float16)a.x, (_Float16)b.x};
            const v2h h1 = {(_Float16)a.y, (_Float16)b.y};
            const v2h h2 = {(_Float16)a.z, (_Float16)b.z};
            const v2h h3 = {(_Float16)a.w, (_Float16)b.w};
            uint4 pk;
            pk.x = __builtin_bit_cast(unsigned int, h0);
            pk.y = __builtin_bit_cast(unsigned int, h1);
            pk.z = __builtin_bit_cast(unsigned int, h2);
            pk.w = __builtin_bit_cast(unsigned int, h3);
            *(uint4*)&cm[c2 * CMP + 4 * xg] = pk;   // 16B aligned
        }
    }
    __syncthreads();
    // pass B: transpose -> rt[xo][c2]
    #pragma unroll
    for (int i = 0; i < 9; ++i) {
        const int idx = tid + 256 * i;              // 16*144 = 2304 dwords
        const int c2 = idx & 15;
        const int xo = idx >> 4;
        rt[xo * 16 + c2] = cm[c2 * CMP + xo];
    }

    // B fragment (L): lane holds L[ch = q*8+j][px = w0w + n]
    v8h bL;
    #pragma unroll
    for (int j = 0; j < 8; ++j)
        bL[j] = (_Float16)left[(q * 8 + j) * HW + row + w0w + n];

    __syncthreads();

    const int pxl = 16 * wid + n;               // local px of this lane
    #pragma unroll
    for (int t = 0; t < 6; ++t) {
        // A fragment (R): lane holds R[ch = q*8+j][xo = 16*(wid+t) + n]
        const uint4 araw = *(const uint4*)&rt[(16 * (wid + t) + n) * 16 + q * 4];
        const v8h aR = __builtin_bit_cast(v8h, araw);
        v4f d = {0.f, 0.f, 0.f, 0.f};
        d = __builtin_amdgcn_mfma_f32_16x16x32_f16(aR, bL, d, 0, 0, 0);
        // D[m = xo-local][n = px-local]: lane holds 4 consecutive xo
        const v2h p01 = {(_Float16)d[0], (_Float16)d[1]};
        const v2h p23 = {(_Float16)d[2], (_Float16)d[3]};
        uint2 pk;
        pk.x = __builtin_bit_cast(unsigned int, p01);
        pk.y = __builtin_bit_cast(unsigned int, p23);
        const int xo = 16 * (wid + t) + 4 * q;      // multiple of 4 -> 8B aligned
        *(uint2*)&sCVx[pxl * XP + xo] = pk;         // one ds_write_b64
    }
    __syncthreads();

    // ---- round 0 (horizontal) + window export, 64 px x all 12 s ----
    const int px = tid & 63;                    // local pixel
    const int sq = tid >> 6;                    // 0..3
    const int wpx = w0B + px;
    const float mind = fmaxf(min_disp[row + wpx], 0.0f);
    const float maxd = fmaxf(max_disp[row + wpx], 0.0f);
    const float sc = (maxd - mind) * INTERVAL;
    const _Float16* rowp = &sCVx[px * XP];

    #pragma unroll
    for (int si = 0; si < 3; ++si) {
        const int s = 3 * sq + si;
        const float imin = fmaf(sc, (float)(s + 1), mind);
        const int kb0 = win_base(imin, sc);
        const int xo0 = kb0 + px;               // k = xo - px
        // 5 aligned dwords + funnel shift if odd start
        const unsigned int* cb = (const unsigned int*)&rowp[xo0 & ~1];
        const unsigned int v0 = cb[0], v1 = cb[1], v2 = cb[2], v3 = cb[3], v4 = cb[4];
        unsigned int u0, u1, u2, u3;
        if (xo0 & 1) {
            u0 = (v0 >> 16) | (v1 << 16);
            u1 = (v1 >> 16) | (v2 << 16);
            u2 = (v2 >> 16) | (v3 << 16);
            u3 = (v3 >> 16) | (v4 << 16);
        } else {
            u0 = v0; u1 = v1; u2 = v2; u3 = v3;
        }
        wbuf[s * HW + row + wpx] = make_uint4(u0, u1, u2, u3);  // coalesced 16B

        float np[3];
        #pragma unroll
        for (int c = 0; c < 3; ++c) {
            const int x = wpx + c - 1;
            np[c] = (x >= 0 && x < W) ? noise_in[s * HW + row + x] : 0.0f;
        }
        float ds, dn;
        eval_w(u0, u1, u2, u3, kb0, wpx, imin, sc, np, ds, dn);
        nbuf0[s * HW + row + wpx] = dn;
    }
}

// ---------------- kernels 2,3: rounds from extracted windows --------------
// PHASE 1: round 1 vertical (nin) -> LDS -> round 2 horizontal -> nout
// PHASE 2: round 3 vertical (nin) -> ds -> nout
template <int PHASE>
__global__ __launch_bounds__(256, 2) void pm_part(
    const float* __restrict__ min_disp, const float* __restrict__ max_disp,
    const uint4* __restrict__ wbuf,
    const float* __restrict__ nin, float* __restrict__ nout)
{
    __shared__ float sN[NPITCH];

    const int w = threadIdx.x;
    const int h = blockIdx.x;                   // fastest -> XCD locality
    const int s = blockIdx.y;
    const int row = h * W;

    // window load: address is position-only -> issues immediately
    const uint4 wb = wbuf[s * HW + row + w];    // one dwordx4, coalesced

    const float mind = fmaxf(min_disp[row + w], 0.0f);
    const float maxd = fmaxf(max_disp[row + w], 0.0f);
    const float sc = (maxd - mind) * INTERVAL;
    const float imin = fmaf(sc, (float)(s + 1), mind);
    const int kb0 = win_base(imin, sc);         // identical ops as build

    if (PHASE == 1 && w < 2)
        sN[w * (NPITCH - 1)] = 0.0f;            // pads 0 and 257 stay zero

    float np[3], ds, dn;
    #pragma unroll
    for (int c = 0; c < 3; ++c) {               // vertical taps
        const int y = h + c - 1;
        np[c] = (y >= 0 && y < H) ? nin[s * HW + y * W + w] : 0.0f;
    }
    eval_w(wb.x, wb.y, wb.z, wb.w, kb0, w, imin, sc, np, ds, dn);

    if (PHASE == 1) {
        sN[1 + w] = dn;                         // disjoint from pads
        __syncthreads();                        // single barrier
        #pragma unroll
        for (int c = 0; c < 3; ++c)
            np[c] = sN[w + c];                  // pads give 0 at edges
        eval_w(wb.x, wb.y, wb.z, wb.w, kb0, w, imin, sc, np, ds, dn);
        nout[s * HW + row + w] = dn;
    } else {
        nout[s * HW + row + w] = ds;
    }
}

extern "C" void kernel_launch(void* const* d_in, const int* in_sizes, int n_in,
                              void* d_out, int out_size, void* d_ws, size_t ws_size,
                              hipStream_t stream) {
    const float* left  = (const float*)d_in[0];
    const float* right = (const float*)d_in[1];
    const float* mind  = (const float*)d_in[2];
    const float* maxd  = (const float*)d_in[3];
    const float* noise = (const float*)d_in[4];
    float* out   = (float*)d_out;
    float* nbuf0 = (float*)d_ws;                   // S*H*W f32 = 1.5 MB
    float* nbuf1 = nbuf0 + S * HW;                 // 1.5 MB
    uint4* wbuf  = (uint4*)(nbuf1 + S * HW);       // S*H*W uint4 = 6.3 MB

    dim3 block(256);
    pm_build_r0<<<dim3(H, 4), block, 0, stream>>>(left, right, mind, maxd,
                                                  noise, wbuf, nbuf0);
    pm_part<1><<<dim3(H, S), block, 0, stream>>>(mind, maxd, wbuf, nbuf0, nbuf1);
    pm_part<2><<<dim3(H, S), block, 0, stream>>>(mind, maxd, wbuf, nbuf1, out);
}